// Round 4
// baseline (108.831 us; speedup 1.0000x reference)
//
#include <hip/hip_runtime.h>
#include <math.h>
#include <float.h>

// Problem constants (from the reference)
#define NN 4096
#define DD 512
#define PP 8
#define QQ 32
#define NB_TOT 40
#define NPW 5                      // neighbors per wave
constexpr float MARGIN = 1.0f;
constexpr float L2W    = 0.005f;
constexpr float EPS    = 1e-6f;

__device__ inline float wave_reduce_sum(float v) {
    v += __shfl_xor(v, 32, 64);
    v += __shfl_xor(v, 16, 64);
    v += __shfl_xor(v,  8, 64);
    v += __shfl_xor(v,  4, 64);
    v += __shfl_xor(v,  2, 64);
    v += __shfl_xor(v,  1, 64);
    return v;
}

__device__ inline float wave_reduce_max(float v) {
    v = fmaxf(v, __shfl_xor(v, 32, 64));
    v = fmaxf(v, __shfl_xor(v, 16, 64));
    v = fmaxf(v, __shfl_xor(v,  8, 64));
    v = fmaxf(v, __shfl_xor(v,  4, 64));
    v = fmaxf(v, __shfl_xor(v,  2, 64));
    v = fmaxf(v, __shfl_xor(v,  1, 64));
    return v;
}

__global__ void init_out_kernel(float* out) {
    if (threadIdx.x == 0) out[0] = 0.0f;
}

// 8192 blocks: block b handles anchor i=b>>1, half h=b&1 (20 neighbors).
// 4 waves x 5 neighbors; whole-row-per-wave fully coalesced 1KB loads,
// 10 row-loads in flight per wave. No barrier, no epilogue here.
// VGPR ~66 -> 7 waves/SIMD via __launch_bounds__(256,7).
__global__ __launch_bounds__(256, 7) void dist_kernel(
    const float* __restrict__ batch,
    const int*   __restrict__ anchors,
    const int*   __restrict__ pos_idx,
    const int*   __restrict__ neg_idx,
    float*       __restrict__ dists,   // [NN][40]
    float*       __restrict__ norms)   // [NN]
{
    const int b    = blockIdx.x;
    const int i    = b >> 1;
    const int h    = b & 1;
    const int tid  = threadIdx.x;
    const int lane = tid & 63;
    const int wave = tid >> 6;                 // 0..3
    const int jb   = h * 20 + wave * NPW;      // 0,5,..,35

    // ---- anchor row, EPS folded in once ----
    const int arow = anchors[i];
    const float* __restrict__ ap = batch + (size_t)arow * DD + lane * 8;
    float4 a0 = *reinterpret_cast<const float4*>(ap);
    float4 a1 = *reinterpret_cast<const float4*>(ap + 4);
    a0.x += EPS; a0.y += EPS; a0.z += EPS; a0.w += EPS;
    a1.x += EPS; a1.y += EPS; a1.z += EPS; a1.w += EPS;

    // ---- row norm (one wave per anchor does it) ----
    if (h == 0 && wave == 0) {
        const float* __restrict__ rp = batch + (size_t)i * DD + lane * 8;
        const float4 r0 = *reinterpret_cast<const float4*>(rp);
        const float4 r1 = *reinterpret_cast<const float4*>(rp + 4);
        float s = r0.x*r0.x + r0.y*r0.y + r0.z*r0.z + r0.w*r0.w
                + r1.x*r1.x + r1.y*r1.y + r1.z*r1.z + r1.w*r1.w;
        s = wave_reduce_sum(s);
        if (lane == 0) norms[i] = sqrtf(s);
    }

    // ---- indices for this wave's 5 neighbors ----
    int idxs[NPW];
    #pragma unroll
    for (int t = 0; t < NPW; ++t) {
        const int j = jb + t;
        idxs[t] = (j < PP) ? pos_idx[i * PP + j] : neg_idx[i * QQ + (j - PP)];
    }

    // ---- all 10 row loads in flight ----
    float4 b0[NPW], b1[NPW];
    #pragma unroll
    for (int t = 0; t < NPW; ++t) {
        const float* __restrict__ bp = batch + (size_t)idxs[t] * DD + lane * 8;
        b0[t] = *reinterpret_cast<const float4*>(bp);
        b1[t] = *reinterpret_cast<const float4*>(bp + 4);
    }

    // ---- squared distances: 2 VALU/elem (EPS pre-folded) ----
    float s[NPW];
    #pragma unroll
    for (int t = 0; t < NPW; ++t) {
        float d, acc = 0.0f;
        d = a0.x - b0[t].x; acc = fmaf(d, d, acc);
        d = a0.y - b0[t].y; acc = fmaf(d, d, acc);
        d = a0.z - b0[t].z; acc = fmaf(d, d, acc);
        d = a0.w - b0[t].w; acc = fmaf(d, d, acc);
        d = a1.x - b1[t].x; acc = fmaf(d, d, acc);
        d = a1.y - b1[t].y; acc = fmaf(d, d, acc);
        d = a1.z - b1[t].z; acc = fmaf(d, d, acc);
        d = a1.w - b1[t].w; acc = fmaf(d, d, acc);
        s[t] = acc;
    }

    #pragma unroll
    for (int t = 0; t < NPW; ++t) s[t] = wave_reduce_sum(s[t]);

    // ---- lanes 0..4 store the 5 distances (coalesced 20B) ----
    float v = s[0];
    v = (lane == 1) ? s[1] : v;
    v = (lane == 2) ? s[2] : v;
    v = (lane == 3) ? s[3] : v;
    v = (lane == 4) ? s[4] : v;
    if (lane < NPW) dists[i * NB_TOT + jb + lane] = sqrtf(v);
}

// 64 blocks x 4 waves; each wave does the logsumexp epilogue for 16 anchors.
__global__ __launch_bounds__(256) void lse_reduce_kernel(
    const float* __restrict__ dists,
    const float* __restrict__ norms,
    float*       __restrict__ out)
{
    const int tid  = threadIdx.x;
    const int lane = tid & 63;
    const int wave = tid >> 6;

    float accum = 0.0f;
    const int abase = (blockIdx.x * 4 + wave) * 16;

    for (int u = 0; u < 16; ++u) {
        const int a = abase + u;
        const float d = (lane < NB_TOT) ? dists[a * NB_TOT + lane] : 0.0f;

        const bool pact = (lane < PP);
        const float pm = wave_reduce_max(pact ? d : -FLT_MAX);
        const float ps = wave_reduce_sum(pact ? expf(d - pm) : 0.0f);
        const float pos_term = pm + logf(ps);

        const bool nact = (lane >= PP) && (lane < NB_TOT);
        const float nv = MARGIN - d;
        const float nm = wave_reduce_max(nact ? nv : -FLT_MAX);
        const float ns = wave_reduce_sum(nact ? expf(nv - nm) : 0.0f);
        const float neg_term = nm + logf(ns);

        if (lane == 0)
            accum += fmaxf(0.0f, pos_term + neg_term) + L2W * norms[a];
    }

    __shared__ float part[4];
    if (lane == 0) part[wave] = accum;
    __syncthreads();
    if (tid == 0)
        atomicAdd(out, (part[0] + part[1] + part[2] + part[3]) * (1.0f / (float)NN));
}

extern "C" void kernel_launch(void* const* d_in, const int* in_sizes, int n_in,
                              void* d_out, int out_size, void* d_ws, size_t ws_size,
                              hipStream_t stream) {
    const float* batch   = (const float*)d_in[0];
    const int*   anchors = (const int*)d_in[1];
    const int*   pos_idx = (const int*)d_in[2];
    const int*   neg_idx = (const int*)d_in[3];
    float*       dists   = (float*)d_ws;                 // NN*40 floats
    float*       norms   = (float*)d_ws + NN * NB_TOT;   // NN floats
    float*       out     = (float*)d_out;

    init_out_kernel<<<1, 1, 0, stream>>>(out);
    dist_kernel<<<2 * NN, 256, 0, stream>>>(batch, anchors, pos_idx, neg_idx, dists, norms);
    lse_reduce_kernel<<<64, 256, 0, stream>>>(dists, norms, out);
}

// Round 5
// 91.353 us; speedup vs baseline: 1.1913x; 1.1913x over previous
//
#include <hip/hip_runtime.h>
#include <math.h>
#include <float.h>

// Problem constants (from the reference)
#define NN 4096
#define DD 512
#define PP 8
#define QQ 32
#define NB_TOT 40
#define NPW 5                      // neighbors per wave (8 waves x 5 = 40)
constexpr float MARGIN = 1.0f;
constexpr float L2W    = 0.005f;
constexpr float EPS    = 1e-6f;

__device__ inline float wave_reduce_sum(float v) {
    v += __shfl_xor(v, 32, 64);
    v += __shfl_xor(v, 16, 64);
    v += __shfl_xor(v,  8, 64);
    v += __shfl_xor(v,  4, 64);
    v += __shfl_xor(v,  2, 64);
    v += __shfl_xor(v,  1, 64);
    return v;
}

__device__ inline float wave_reduce_max(float v) {
    v = fmaxf(v, __shfl_xor(v, 32, 64));
    v = fmaxf(v, __shfl_xor(v, 16, 64));
    v = fmaxf(v, __shfl_xor(v,  8, 64));
    v = fmaxf(v, __shfl_xor(v,  4, 64));
    v = fmaxf(v, __shfl_xor(v,  2, 64));
    v = fmaxf(v, __shfl_xor(v,  1, 64));
    return v;
}

// One block per anchor; 8 waves x 5 neighbors each. Whole-row-per-wave fully
// coalesced 1KB loads, 10 row-load instrs in flight per wave, ~70 VGPR ->
// ~7 waves/SIMD. Epilogue fused (wave 0), per-anchor scalar -> ws[i].
__global__ __launch_bounds__(512) void dist_kernel(
    const float* __restrict__ batch,
    const int*   __restrict__ anchors,
    const int*   __restrict__ pos_idx,
    const int*   __restrict__ neg_idx,
    float*       __restrict__ ws)
{
    const int i    = blockIdx.x;
    const int tid  = threadIdx.x;
    const int lane = tid & 63;
    const int wave = tid >> 6;                 // 0..7
    const int jb   = wave * NPW;               // 0,5,..,35

    __shared__ float dist[NB_TOT];
    __shared__ float norm_sh;

    // ---- anchor row, EPS folded in once ----
    const int arow = anchors[i];
    const float* __restrict__ ap = batch + (size_t)arow * DD + lane * 8;
    float4 a0 = *reinterpret_cast<const float4*>(ap);
    float4 a1 = *reinterpret_cast<const float4*>(ap + 4);
    a0.x += EPS; a0.y += EPS; a0.z += EPS; a0.w += EPS;
    a1.x += EPS; a1.y += EPS; a1.z += EPS; a1.w += EPS;

    // ---- wave 7 computes ||batch[i]|| (row usually L1/L2-hot) ----
    if (wave == 7) {
        const float* __restrict__ rp = batch + (size_t)i * DD + lane * 8;
        const float4 r0 = *reinterpret_cast<const float4*>(rp);
        const float4 r1 = *reinterpret_cast<const float4*>(rp + 4);
        float s = r0.x*r0.x + r0.y*r0.y + r0.z*r0.z + r0.w*r0.w
                + r1.x*r1.x + r1.y*r1.y + r1.z*r1.z + r1.w*r1.w;
        s = wave_reduce_sum(s);
        if (lane == 0) norm_sh = sqrtf(s);
    }

    // ---- this wave's 5 neighbor indices (wave-uniform scalar loads) ----
    int idxs[NPW];
    #pragma unroll
    for (int t = 0; t < NPW; ++t) {
        const int j = jb + t;
        idxs[t] = (j < PP) ? pos_idx[i * PP + j] : neg_idx[i * QQ + (j - PP)];
    }

    // ---- all 10 row-load instructions in flight ----
    float4 b0[NPW], b1[NPW];
    #pragma unroll
    for (int t = 0; t < NPW; ++t) {
        const float* __restrict__ bp = batch + (size_t)idxs[t] * DD + lane * 8;
        b0[t] = *reinterpret_cast<const float4*>(bp);
        b1[t] = *reinterpret_cast<const float4*>(bp + 4);
    }

    // ---- squared distances: 2 VALU/elem (EPS pre-folded) ----
    float s[NPW];
    #pragma unroll
    for (int t = 0; t < NPW; ++t) {
        float d, acc = 0.0f;
        d = a0.x - b0[t].x; acc = fmaf(d, d, acc);
        d = a0.y - b0[t].y; acc = fmaf(d, d, acc);
        d = a0.z - b0[t].z; acc = fmaf(d, d, acc);
        d = a0.w - b0[t].w; acc = fmaf(d, d, acc);
        d = a1.x - b1[t].x; acc = fmaf(d, d, acc);
        d = a1.y - b1[t].y; acc = fmaf(d, d, acc);
        d = a1.z - b1[t].z; acc = fmaf(d, d, acc);
        d = a1.w - b1[t].w; acc = fmaf(d, d, acc);
        s[t] = acc;
    }

    // ---- 5 independent shuffle-reduce chains ----
    #pragma unroll
    for (int t = 0; t < NPW; ++t) s[t] = wave_reduce_sum(s[t]);

    // ---- lanes 0..4 store the 5 distances into LDS ----
    float v = s[0];
    v = (lane == 1) ? s[1] : v;
    v = (lane == 2) ? s[2] : v;
    v = (lane == 3) ? s[3] : v;
    v = (lane == 4) ? s[4] : v;
    if (lane < NPW) dist[jb + lane] = sqrtf(v);

    __syncthreads();

    // ---- wave-parallel logsumexp epilogue (lanes 0..39 of wave 0) ----
    if (wave == 0) {
        const float d = (lane < NB_TOT) ? dist[lane] : 0.0f;

        const bool pact = (lane < PP);
        const float pm = wave_reduce_max(pact ? d : -FLT_MAX);
        const float ps = wave_reduce_sum(pact ? expf(d - pm) : 0.0f);
        const float pos_term = pm + logf(ps);

        const bool nact = (lane >= PP) && (lane < NB_TOT);
        const float nv = MARGIN - d;
        const float nm = wave_reduce_max(nact ? nv : -FLT_MAX);
        const float ns = wave_reduce_sum(nact ? expf(nv - nm) : 0.0f);
        const float neg_term = nm + logf(ns);

        if (lane == 0)
            ws[i] = fmaxf(0.0f, pos_term + neg_term) + L2W * norm_sh;
    }
}

// Single-block final reduction: out = mean(ws[0..N))
__global__ __launch_bounds__(256) void reduce_kernel(
    const float* __restrict__ ws, float* __restrict__ out)
{
    const int tid  = threadIdx.x;
    const int lane = tid & 63;
    const int wave = tid >> 6;

    const float4* __restrict__ w4 = reinterpret_cast<const float4*>(ws);
    float s = 0.0f;
    #pragma unroll
    for (int k = 0; k < 4; ++k) {          // 1024 float4 total
        const float4 v = w4[tid + 256 * k];
        s += v.x + v.y + v.z + v.w;
    }
    s = wave_reduce_sum(s);

    __shared__ float part[4];
    if (lane == 0) part[wave] = s;
    __syncthreads();
    if (tid == 0)
        out[0] = (part[0] + part[1] + part[2] + part[3]) * (1.0f / (float)NN);
}

extern "C" void kernel_launch(void* const* d_in, const int* in_sizes, int n_in,
                              void* d_out, int out_size, void* d_ws, size_t ws_size,
                              hipStream_t stream) {
    const float* batch   = (const float*)d_in[0];
    const int*   anchors = (const int*)d_in[1];
    const int*   pos_idx = (const int*)d_in[2];
    const int*   neg_idx = (const int*)d_in[3];
    float*       ws      = (float*)d_ws;
    float*       out     = (float*)d_out;

    dist_kernel<<<NN, 512, 0, stream>>>(batch, anchors, pos_idx, neg_idx, ws);
    reduce_kernel<<<1, 256, 0, stream>>>(ws, out);
}